// Round 8
// baseline (219.082 us; speedup 1.0000x reference)
//
#include <hip/hip_runtime.h>
#include <hip/hip_cooperative_groups.h>
#include <math.h>

namespace cg = cooperative_groups;

// Problem constants
#define CCd     0.01
#define SCd     0.1         // sqrt(C)
#define MAXNRMd 9.99        // (1-0.001)/sqrt(C)
#define MINNd   1e-5
#define DD      1024
#define NK      25          // K*N support rows
#define NQ      75          // K*Q query rows
#define NROWS   100
#define KCLS    5
#define NAUG    40
#define GRIDB   200         // cooperative grid blocks (max needed by coef phase)

__device__ __forceinline__ double wave_reduce_d(double v){
#pragma unroll
  for (int o = 32; o > 0; o >>= 1) v += __shfl_xor(v, o);
  return v;
}

__device__ __forceinline__ double hyp_dist_d(double xy, double x2, double y2){
  double a    = 1.0 - 2.0*CCd*xy + CCd*y2;
  double b    = 1.0 - CCd*x2;
  double num2 = a*a*x2 + b*b*y2 - 2.0*a*b*xy;
  double den  = 1.0 - 2.0*CCd*xy + CCd*CCd*x2*y2;
  double nrm  = sqrt(fmax(num2, 0.0)) / fmax(den, MINNd);
  double z    = SCd * nrm;
  z = fmin(fmax(z, -1.0 + MINNd), 1.0 - MINNd);
  return 10.0 * log((1.0 + z) / (1.0 - z));   // (2/sc)*artanh(z)
}

// lam*a and lam from ||p||^2 (k-space conversion weights)
__device__ __forceinline__ void kweights(double pp, double* la, double* l_out){
  double a  = 2.0/(1.0 + CCd*pp);
  double k2 = a*a*pp;
  double l  = 1.0/sqrt(fmax(1.0 - CCd*k2, MINNd));
  *la = l*a; *l_out = l;
}

__global__ __launch_bounds__(256)
void k_fused(const float* __restrict__ feat, const int* __restrict__ label,
             const float* __restrict__ noise, float* __restrict__ out,
             float* __restrict__ wsf)
{
  cg::grid_group grid = cg::this_grid();
  const int bid = blockIdx.x, t = threadIdx.x;
  const int lane = t & 63, wv = t >> 6;

  // ws layout (doubles start at 105*1024*4 = 430080 B, 8-aligned)
  float*  P       = wsf;                       // [100][1024] projected points
  float*  protoNr = P + NROWS*DD;              // [5][1024] unscaled new protos
  double* p2d     = (double*)(protoNr + KCLS*DD);
  double* distS   = p2d + NROWS;               // [75][5]
  double* lossQ   = distS + NQ*KCLS;           // [75]
  double* std_g   = lossQ + NQ;                // [5][1024]
  double* mkr_g   = std_g + KCLS*DD;           // [5][1024] raw weighted mean_k
  double* mk2part = mkr_g + KCLS*DD;           // [20]
  double* coefS_g = mk2part + 32;              // [200]
  double* coefV_g = coefS_g + KCLS*NAUG;       // [200]
  double* lamJ_g  = coefV_g + KCLS*NAUG;       // [200]
  double* mk2Np   = lamJ_g + KCLS*NAUG;       // [20]
  int*    predS   = (int*)(mk2Np + 32);        // [75]

  __shared__ double redA[4];
  __shared__ double redB[4][10];
  __shared__ double sWA[80], sWL[80], sWM[80];
  __shared__ int    sRows[80];
  __shared__ double sScal[4];
  __shared__ double redD[4][2];
  __shared__ double sCV[NAUG], sSup[5];
  __shared__ double redF[4][5];

  // ---------- Phase A: expmap0 + project (blocks 0..99, one per row) ----------
  if (bid < NROWS){
    const int r = bid;
    const float4 v = reinterpret_cast<const float4*>(feat + r*DD)[t];
    double ss = (double)v.x*v.x + (double)v.y*v.y + (double)v.z*v.z + (double)v.w*v.w;
    ss = wave_reduce_d(ss);
    if (lane == 0) redA[wv] = ss;
    __syncthreads();
    ss = redA[0] + redA[1] + redA[2] + redA[3];
    double un = fmax(sqrt(ss), MINNd);
    double th = tanh(SCd*un);
    double na = th * 10.0;                   // ||expmap0(u)||
    double factor, pn;
    if (na > MAXNRMd) { factor = MAXNRMd/un; pn = MAXNRMd; }
    else              { factor = th/(SCd*un); pn = na; }
    float4 o;
    o.x = (float)(v.x*factor); o.y = (float)(v.y*factor);
    o.z = (float)(v.z*factor); o.w = (float)(v.w*factor);
    reinterpret_cast<float4*>(P + r*DD)[t] = o;
    if (t == 0) p2d[r] = pn*pn;
  }
  grid.sync();

  // ---------- Phase B: dist(queries, protoP) + pred (blocks 0..74, proto folded) ----------
  if (bid < NQ){
    const int q = bid;
    const float* xq = P + (NK+q)*DD;
    double ss[5], rd[5];
#pragma unroll
    for (int c = 0; c < 5; c++){
      double la[5], wsum = 0.0;
#pragma unroll
      for (int i = 0; i < 5; i++){
        double lv; kweights(p2d[c*5+i], &la[i], &lv); wsum += lv;
      }
      double ssc = 0.0, rdc = 0.0;
#pragma unroll
      for (int k = 0; k < 4; k++){
        int d = t + 256*k;
        double s = 0.0;
#pragma unroll
        for (int i = 0; i < 5; i++) s += la[i]*(double)P[(c*5+i)*DD + d];
        s /= wsum;
        ssc += s*s; rdc += s*(double)xq[d];
      }
      ss[c] = wave_reduce_d(ssc);
      rd[c] = wave_reduce_d(rdc);
    }
    if (lane == 0){
#pragma unroll
      for (int c = 0; c < 5; c++){ redB[wv][c] = ss[c]; redB[wv][5+c] = rd[c]; }
    }
    __syncthreads();
    if (t == 0){
      double x2 = p2d[NK+q];
      double best = 1e300; int bi = 0;
#pragma unroll
      for (int c = 0; c < 5; c++){
        double sst = redB[0][c]+redB[1][c]+redB[2][c]+redB[3][c];
        double rdt = redB[0][5+c]+redB[1][5+c]+redB[2][5+c]+redB[3][5+c];
        double sf  = 1.0/(1.0 + sqrt(fmax(1.0 - CCd*sst, 0.0)));
        double dv  = hyp_dist_d(sf*rdt, x2, sst*sf*sf);
        distS[q*5 + c] = dv;
        if (dv < best){ best = dv; bi = c; }   // first-min == argmax(-dist)
      }
      predS[q] = bi;
    }
  }
  grid.sync();

  // ---------- Phase C: per-(class,chunk) masked stats (blocks 0..19) ----------
  if (bid < 4*KCLS){
    const int c = bid >> 2, chunk = bid & 3;
    if (t < 80){
      int row; double m;
      if (t < 5){ row = c*5 + t; m = 1.0; }
      else      { row = NK + (t-5); m = (predS[t-5] == c) ? 1.0 : 0.0; }
      sRows[t] = row;
      double la, l; kweights(p2d[row], &la, &l);
      sWA[t] = m*la; sWL[t] = m*l; sWM[t] = m;
    }
    __syncthreads();
    if (t == 0){
      double wsum = 0.0, cnt = 0.0;
      for (int i = 0; i < 80; i++){ wsum += sWL[i]; cnt += sWM[i]; }
      sScal[0] = wsum; sScal[1] = cnt;
    }
    __syncthreads();
    const double wsum = sScal[0], cnt = sScal[1];
    const int d = chunk*256 + t;
    double mkd = 0.0, mud = 0.0, sqd = 0.0;
    for (int i = 0; i < 80; i++){
      int row = sRows[i];
      mkd += sWA[i]*(double)P[row*DD + d];
      double e = (double)feat[row*DD + d];
      mud += sWM[i]*e;
      sqd += sWM[i]*e*e;
    }
    mkd /= wsum;
    mud /= cnt;
    double var = (sqd - cnt*mud*mud)/(cnt - 1.0);
    std_g[c*DD + d] = sqrt(fmax(var, 0.0));
    mkr_g[c*DD + d] = mkd;
    double s = wave_reduce_d(mkd*mkd);
    if (lane == 0) redA[wv] = s;
    __syncthreads();
    if (t == 0) mk2part[bid] = redA[0] + redA[1] + redA[2] + redA[3];
  }
  grid.sync();

  // ---------- Phase D: per-(class,noise-row) ex coefficients (all 200 blocks) ----------
  {
    const int c = bid / NAUG, j = bid % NAUG;
    const float*  nzr = noise + (c*NAUG + j)*DD;
    const double* st  = std_g + c*DD;
    const double* mk  = mkr_g + c*DD;
    double un2 = 0.0, rdd = 0.0;
#pragma unroll
    for (int k = 0; k < 4; k++){
      int d = t + 256*k;
      double v = (double)nzr[d]*st[d];
      un2 += v*v;
      rdd += v*mk[d];
    }
    un2 = wave_reduce_d(un2);
    rdd = wave_reduce_d(rdd);
    if (lane == 0){ redD[wv][0] = un2; redD[wv][1] = rdd; }
    __syncthreads();
    if (t == 0){
      double s_un2 = redD[0][0]+redD[1][0]+redD[2][0]+redD[3][0];
      double rdot  = redD[0][1]+redD[1][1]+redD[2][1]+redD[3][1];
      double mk2 = mk2part[c*4+0]+mk2part[c*4+1]+mk2part[c*4+2]+mk2part[c*4+3];
      double sf  = 1.0/(1.0 + sqrt(fmax(1.0 - CCd*mk2, 0.0)));
      double sp2 = mk2*sf*sf;                 // ||s_p||^2
      double lamx = 2.0/fmax(1.0 - CCd*sp2, MINNd);
      double ptf  = 1.0 - CCd*sp2;            // ptransp0 factor == mobius B
      double s_dot = sf*rdot;                 // v . s_p
      double unv = sqrt(s_un2);               // ||v||
      double unp = fmax(ptf*unv, MINNd);      // ||pt||
      double g0  = tanh(SCd*lamx*unp*0.5)/(SCd*unp);
      double g   = g0*ptf;                    // second = g * v
      double y2  = g*g*s_un2;
      double xy  = g*s_dot;
      double A   = 1.0 + 2.0*CCd*xy + CCd*y2;
      double B   = ptf;
      double den = fmax(1.0 + 2.0*CCd*xy + CCd*CCd*sp2*y2, MINNd);
      double ex2 = (A*A*sp2 + 2.0*A*B*g*s_dot + B*B*g*g*s_un2)/(den*den);
      double ae  = 2.0/(1.0 + CCd*ex2);
      double k2e = ae*ae*ex2;
      double le  = 1.0/sqrt(fmax(1.0 - CCd*k2e, MINNd));
      coefS_g[c*NAUG + j] = le*ae*A/den;
      coefV_g[c*NAUG + j] = le*ae*B*g/den;
      lamJ_g[c*NAUG + j]  = le;
    }
  }
  grid.sync();

  // ---------- Phase E: assemble 45-pt mean (blocks 0..19); UNSCALED proto ----------
  if (bid < 4*KCLS){
    const int c = bid >> 2, chunk = bid & 3;
    if (t < NAUG) sCV[t] = coefV_g[c*NAUG + t];
    if (t == 0){
      double lsum = 0.0, sS = 0.0;
#pragma unroll
      for (int i = 0; i < 5; i++){
        double la, l; kweights(p2d[c*5+i], &la, &l);
        sSup[i] = la; lsum += l;
      }
      for (int j = 0; j < NAUG; j++){ lsum += lamJ_g[c*NAUG+j]; sS += coefS_g[c*NAUG+j]; }
      double mk2 = mk2part[c*4+0]+mk2part[c*4+1]+mk2part[c*4+2]+mk2part[c*4+3];
      double sf  = 1.0/(1.0 + sqrt(fmax(1.0 - CCd*mk2, 0.0)));
      sScal[0] = lsum; sScal[1] = sS; sScal[2] = sf;
    }
    __syncthreads();
    const int d = chunk*256 + t;
    double val = sScal[1]*sScal[2]*mkr_g[c*DD + d];      // sumS * sp_d
#pragma unroll
    for (int i = 0; i < 5; i++) val += sSup[i]*(double)P[(c*5+i)*DD + d];
    double na = 0.0;
    for (int j = 0; j < NAUG; j++) na += sCV[j]*(double)noise[(c*NAUG + j)*DD + d];
    val += std_g[c*DD + d]*na;
    val /= sScal[0];
    protoNr[c*DD + d] = (float)val;                      // unscaled mean_k
    double s = wave_reduce_d(val*val);
    if (lane == 0) redA[wv] = s;
    __syncthreads();
    if (t == 0) mk2Np[bid] = redA[0] + redA[1] + redA[2] + redA[3];
  }
  grid.sync();

  // ---------- Phase F: dist_new + y_pred softmax + per-query loss (blocks 0..74) ----------
  if (bid < NQ){
    const int q = bid;
    const float* xq = P + (NK+q)*DD;
    double acc[5] = {0,0,0,0,0};
#pragma unroll
    for (int k = 0; k < 4; k++){
      int d = t + 256*k;
      double x = (double)xq[d];
#pragma unroll
      for (int c = 0; c < 5; c++) acc[c] += x*(double)protoNr[c*DD + d];
    }
#pragma unroll
    for (int c = 0; c < 5; c++) acc[c] = wave_reduce_d(acc[c]);
    if (lane == 0){
#pragma unroll
      for (int c = 0; c < 5; c++) redF[wv][c] = acc[c];
    }
    __syncthreads();
    if (t == 0){
      double x2 = p2d[NK+q];
      double v[5]; double mx = -1e300;
#pragma unroll
      for (int c = 0; c < 5; c++){
        double mk2N = mk2Np[c*4+0]+mk2Np[c*4+1]+mk2Np[c*4+2]+mk2Np[c*4+3];
        double sfN  = 1.0/(1.0 + sqrt(fmax(1.0 - CCd*mk2N, 0.0)));
        double dot  = sfN*(redF[0][c]+redF[1][c]+redF[2][c]+redF[3][c]);
        v[c] = -hyp_dist_d(dot, x2, mk2N*sfN*sfN);
        mx = fmax(mx, v[c]);
      }
      double se = 0.0;
#pragma unroll
      for (int c = 0; c < 5; c++){ v[c] = exp(v[c]-mx); se += v[c]; }
      double inv = 1.0/se;
#pragma unroll
      for (int c = 0; c < 5; c++) out[q*5 + c] = (float)(v[c]*inv);

      // ll = log_softmax(log_softmax(-distS)); lossQ = ll[label]
      double u[5]; mx = -1e300;
#pragma unroll
      for (int c = 0; c < 5; c++){ u[c] = -distS[q*5+c]; mx = fmax(mx, u[c]); }
      double s1 = 0.0;
#pragma unroll
      for (int c = 0; c < 5; c++) s1 += exp(u[c]-mx);
      double lse1 = mx + log(s1);
#pragma unroll
      for (int c = 0; c < 5; c++) u[c] -= lse1;
      double mx2 = -1e300;
#pragma unroll
      for (int c = 0; c < 5; c++) mx2 = fmax(mx2, u[c]);
      double s2 = 0.0;
#pragma unroll
      for (int c = 0; c < 5; c++) s2 += exp(u[c]-mx2);
      double lse2 = mx2 + log(s2);
      lossQ[q] = u[label[NQ + q]] - lse2;
    }
  }
  grid.sync();

  // ---------- Phase G: final loss reduction (block 0) ----------
  if (bid == 0){
    double v = (t < NQ) ? lossQ[t] : 0.0;
    v = wave_reduce_d(v);
    if (lane == 0) redA[wv] = v;
    __syncthreads();
    if (t == 0) out[NQ*KCLS] = (float)(-(redA[0]+redA[1]+redA[2]+redA[3])/75.0);
  }
}

extern "C" void kernel_launch(void* const* d_in, const int* in_sizes, int n_in,
                              void* d_out, int out_size, void* d_ws, size_t ws_size,
                              hipStream_t stream) {
  const float* feat  = (const float*)d_in[0];
  const int*   label = (const int*)d_in[1];
  const float* noise = (const float*)d_in[2];
  float* out = (float*)d_out;
  float* wsf = (float*)d_ws;

  void* args[] = { (void*)&feat, (void*)&label, (void*)&noise,
                   (void*)&out, (void*)&wsf };
  hipLaunchCooperativeKernel((const void*)k_fused, dim3(GRIDB), dim3(256),
                             args, 0, stream);
}

// Round 15
// 101.052 us; speedup vs baseline: 2.1680x; 2.1680x over previous
//
#include <hip/hip_runtime.h>
#include <hip/hip_bf16.h>
#include <math.h>

// Problem constants
#define CCd     0.01
#define SCd     0.1         // sqrt(C)
#define MAXNRMd 9.99        // (1-0.001)/sqrt(C)
#define MINNd   1e-5
#define DD      1024
#define NK      25          // K*N support rows
#define NQ      75          // K*Q query rows
#define NROWS   100
#define KCLS    5
#define NAUG    40

__device__ __forceinline__ double wave_reduce_d(double v){
#pragma unroll
  for (int o = 32; o > 0; o >>= 1) v += __shfl_xor(v, o);
  return v;
}

__device__ __forceinline__ double hyp_dist_d(double xy, double x2, double y2){
  double a    = 1.0 - 2.0*CCd*xy + CCd*y2;
  double b    = 1.0 - CCd*x2;
  double num2 = a*a*x2 + b*b*y2 - 2.0*a*b*xy;
  double den  = 1.0 - 2.0*CCd*xy + CCd*CCd*x2*y2;
  double nrm  = sqrt(fmax(num2, 0.0)) / fmax(den, MINNd);
  double z    = SCd * nrm;
  z = fmin(fmax(z, -1.0 + MINNd), 1.0 - MINNd);
  return 10.0 * log((1.0 + z) / (1.0 - z));   // (2/sc)*artanh(z)
}

// lam*a and lam from ||p||^2 (k-space conversion weights)
__device__ __forceinline__ void kweights(double pp, double* la, double* l_out){
  double a  = 2.0/(1.0 + CCd*pp);
  double k2 = a*a*pp;
  double l  = 1.0/sqrt(fmax(1.0 - CCd*k2, MINNd));
  *la = l*a; *l_out = l;
}

// ---------- K1: expmap0 + project, one block per row (+ zero the loss counter) ----------
__global__ __launch_bounds__(256)
void k_expmap(const float* __restrict__ feat, float* __restrict__ P,
              double* __restrict__ p2d, int* __restrict__ cnt){
  const int r = blockIdx.x, t = threadIdx.x;
  if (r == 0 && t == 0) *cnt = 0;          // reset finalize counter each launch
  const float4 v = reinterpret_cast<const float4*>(feat + r*DD)[t];
  double ss = (double)v.x*v.x + (double)v.y*v.y + (double)v.z*v.z + (double)v.w*v.w;
  __shared__ double red[4];
  ss = wave_reduce_d(ss);
  if ((t & 63) == 0) red[t >> 6] = ss;
  __syncthreads();
  ss = red[0] + red[1] + red[2] + red[3];
  double un = fmax(sqrt(ss), MINNd);
  double th = tanh(SCd*un);
  double na = th * 10.0;                   // ||expmap0(u)||
  double factor, pn;
  if (na > MAXNRMd) { factor = MAXNRMd/un; pn = MAXNRMd; }
  else              { factor = th/(SCd*un); pn = na; }
  float4 o;
  o.x = (float)(v.x*factor); o.y = (float)(v.y*factor);
  o.z = (float)(v.z*factor); o.w = (float)(v.w*factor);
  reinterpret_cast<float4*>(P + r*DD)[t] = o;
  if (t == 0) p2d[r] = pn*pn;
}

// ---------- K2: dist(queries, proto) + pred, proto folded in (one block per query) ----------
__global__ __launch_bounds__(256)
void k_dist1(const float* __restrict__ P, const double* __restrict__ p2d,
             double* __restrict__ distS, int* __restrict__ predS){
  const int q = blockIdx.x, t = threadIdx.x;
  const int lane = t & 63, wv = t >> 6;
  const float* xq = P + (NK+q)*DD;
  __shared__ double redB[4][10];
  double ss[5], rd[5];
#pragma unroll
  for (int c = 0; c < 5; c++){
    double la[5], wsum = 0.0;
#pragma unroll
    for (int i = 0; i < 5; i++){
      double lv; kweights(p2d[c*5+i], &la[i], &lv); wsum += lv;
    }
    double ssc = 0.0, rdc = 0.0;
#pragma unroll
    for (int k = 0; k < 4; k++){
      int d = t + 256*k;
      double s = 0.0;
#pragma unroll
      for (int i = 0; i < 5; i++) s += la[i]*(double)P[(c*5+i)*DD + d];
      s /= wsum;
      ssc += s*s; rdc += s*(double)xq[d];
    }
    ss[c] = wave_reduce_d(ssc);
    rd[c] = wave_reduce_d(rdc);
  }
  if (lane == 0){
#pragma unroll
    for (int c = 0; c < 5; c++){ redB[wv][c] = ss[c]; redB[wv][5+c] = rd[c]; }
  }
  __syncthreads();
  if (t == 0){
    double x2 = p2d[NK+q];
    double best = 1e300; int bi = 0;
#pragma unroll
    for (int c = 0; c < 5; c++){
      double sst = redB[0][c]+redB[1][c]+redB[2][c]+redB[3][c];
      double rdt = redB[0][5+c]+redB[1][5+c]+redB[2][5+c]+redB[3][5+c];
      double sf  = 1.0/(1.0 + sqrt(fmax(1.0 - CCd*sst, 0.0)));
      double dv  = hyp_dist_d(sf*rdt, x2, sst*sf*sf);
      distS[q*5 + c] = dv;
      if (dv < best){ best = dv; bi = c; }   // first-min == argmax(-dist)
    }
    predS[q] = bi;
  }
}

// ---------- K3: per-(class,dim-chunk) masked stats ----------
__global__ __launch_bounds__(256)
void k_stats(const float* __restrict__ feat, const float* __restrict__ P,
             const double* __restrict__ p2d, const int* __restrict__ predS,
             double* __restrict__ std_g, double* __restrict__ mkr_g,
             double* __restrict__ mk2part){
  const int c = blockIdx.x >> 2, chunk = blockIdx.x & 3, t = threadIdx.x;
  __shared__ double wA[80], wL[80], wM[80], scal[2], red[4];
  __shared__ int rows[80];
  if (t < 80){
    int row; double m;
    if (t < 5){ row = c*5 + t; m = 1.0; }
    else      { row = NK + (t-5); m = (predS[t-5] == c) ? 1.0 : 0.0; }
    rows[t] = row;
    double la, l; kweights(p2d[row], &la, &l);
    wA[t] = m*la; wL[t] = m*l; wM[t] = m;
  }
  __syncthreads();
  if (t == 0){
    double wsum = 0.0, cnt = 0.0;
    for (int i = 0; i < 80; i++){ wsum += wL[i]; cnt += wM[i]; }
    scal[0] = wsum; scal[1] = cnt;
  }
  __syncthreads();
  const double wsum = scal[0], cnt = scal[1];
  const int d = chunk*256 + t;
  double mkd = 0.0, mud = 0.0, sqd = 0.0;
  for (int i = 0; i < 80; i++){
    int row = rows[i];
    mkd += wA[i]*(double)P[row*DD + d];
    double e = (double)feat[row*DD + d];
    mud += wM[i]*e;
    sqd += wM[i]*e*e;
  }
  mkd /= wsum;
  mud /= cnt;
  double var = (sqd - cnt*mud*mud)/(cnt - 1.0);
  std_g[c*DD + d] = sqrt(fmax(var, 0.0));
  mkr_g[c*DD + d] = mkd;
  double s = wave_reduce_d(mkd*mkd);
  if ((t & 63) == 0) red[t >> 6] = s;
  __syncthreads();
  if (t == 0) mk2part[blockIdx.x] = red[0] + red[1] + red[2] + red[3];
}

// ---------- K4: per-(class,noise-row) closed-form ex coefficients ----------
__global__ __launch_bounds__(256)
void k_coef(const float* __restrict__ noise, const double* __restrict__ std_g,
            const double* __restrict__ mkr_g, const double* __restrict__ mk2part,
            double* __restrict__ coefS_g, double* __restrict__ coefV_g,
            double* __restrict__ lamJ_g){
  const int j = blockIdx.x, c = blockIdx.y, t = threadIdx.x;
  const float*  nzr = noise + (c*NAUG + j)*DD;
  const double* st  = std_g + c*DD;
  const double* mk  = mkr_g + c*DD;
  double un2 = 0.0, rd = 0.0;
#pragma unroll
  for (int k = 0; k < 4; k++){
    int d = t + 256*k;
    double v = (double)nzr[d]*st[d];
    un2 += v*v;
    rd  += v*mk[d];
  }
  __shared__ double red[4][2];
  un2 = wave_reduce_d(un2);
  rd  = wave_reduce_d(rd);
  if ((t & 63) == 0){ red[t >> 6][0] = un2; red[t >> 6][1] = rd; }
  __syncthreads();
  if (t == 0){
    double s_un2 = red[0][0]+red[1][0]+red[2][0]+red[3][0];
    double rdot  = red[0][1]+red[1][1]+red[2][1]+red[3][1];
    double mk2 = mk2part[c*4+0]+mk2part[c*4+1]+mk2part[c*4+2]+mk2part[c*4+3];
    double sf  = 1.0/(1.0 + sqrt(fmax(1.0 - CCd*mk2, 0.0)));
    double sp2 = mk2*sf*sf;                 // ||s_p||^2
    double lamx = 2.0/fmax(1.0 - CCd*sp2, MINNd);
    double ptf  = 1.0 - CCd*sp2;            // ptransp0 factor == mobius B
    double s_dot = sf*rdot;                 // v . s_p
    double unv = sqrt(s_un2);               // ||v||
    double unp = fmax(ptf*unv, MINNd);      // ||pt||
    double g0  = tanh(SCd*lamx*unp*0.5)/(SCd*unp);
    double g   = g0*ptf;                    // second = g * v
    double y2  = g*g*s_un2;
    double xy  = g*s_dot;
    double A   = 1.0 + 2.0*CCd*xy + CCd*y2;
    double B   = ptf;
    double den = fmax(1.0 + 2.0*CCd*xy + CCd*CCd*sp2*y2, MINNd);
    double ex2 = (A*A*sp2 + 2.0*A*B*g*s_dot + B*B*g*g*s_un2)/(den*den);
    double ae  = 2.0/(1.0 + CCd*ex2);
    double k2e = ae*ae*ex2;
    double le  = 1.0/sqrt(fmax(1.0 - CCd*k2e, MINNd));
    coefS_g[c*NAUG + j] = le*ae*A/den;
    coefV_g[c*NAUG + j] = le*ae*B*g/den;
    lamJ_g[c*NAUG + j]  = le;
  }
}

// ---------- K5: assemble 45-pt mean per (class,chunk); UNSCALED proto + partial norm ----------
__global__ __launch_bounds__(256)
void k_asm(const float* __restrict__ noise, const float* __restrict__ P,
           const double* __restrict__ p2d, const double* __restrict__ std_g,
           const double* __restrict__ mkr_g, const double* __restrict__ mk2part,
           const double* __restrict__ coefS_g, const double* __restrict__ coefV_g,
           const double* __restrict__ lamJ_g,
           float* __restrict__ protoNr, double* __restrict__ mk2Np){
  const int c = blockIdx.x >> 2, chunk = blockIdx.x & 3, t = threadIdx.x;
  __shared__ double cV[NAUG], supC[5], scal[3], red[4];
  if (t < NAUG) cV[t] = coefV_g[c*NAUG + t];
  if (t == 0){
    double lsum = 0.0, sS = 0.0;
#pragma unroll
    for (int i = 0; i < 5; i++){
      double la, l; kweights(p2d[c*5+i], &la, &l);
      supC[i] = la; lsum += l;
    }
    for (int j = 0; j < NAUG; j++){ lsum += lamJ_g[c*NAUG+j]; sS += coefS_g[c*NAUG+j]; }
    double mk2 = mk2part[c*4+0]+mk2part[c*4+1]+mk2part[c*4+2]+mk2part[c*4+3];
    double sf  = 1.0/(1.0 + sqrt(fmax(1.0 - CCd*mk2, 0.0)));
    scal[0] = lsum; scal[1] = sS; scal[2] = sf;
  }
  __syncthreads();
  const int d = chunk*256 + t;
  double val = scal[1]*scal[2]*mkr_g[c*DD + d];      // sumS * sp_d
#pragma unroll
  for (int i = 0; i < 5; i++) val += supC[i]*(double)P[(c*5+i)*DD + d];
  double na = 0.0;
  for (int j = 0; j < NAUG; j++) na += cV[j]*(double)noise[(c*NAUG + j)*DD + d];
  val += std_g[c*DD + d]*na;
  val /= scal[0];
  protoNr[c*DD + d] = (float)val;                    // unscaled mean_k
  double s = wave_reduce_d(val*val);
  if ((t & 63) == 0) red[t >> 6] = s;
  __syncthreads();
  if (t == 0) mk2Np[blockIdx.x] = red[0] + red[1] + red[2] + red[3];
}

// ---------- K6: dist_new + y_pred + per-query loss + last-block loss finalize ----------
__global__ __launch_bounds__(256)
void k_dist2(const float* __restrict__ P, const float* __restrict__ protoNr,
             const double* __restrict__ p2d, const double* __restrict__ mk2Np,
             const double* __restrict__ distS, const int* __restrict__ label,
             float* __restrict__ out, double* __restrict__ lossQ,
             int* __restrict__ cnt){
  const int q = blockIdx.x, t = threadIdx.x;
  const float* xq = P + (NK+q)*DD;
  double acc[5] = {0,0,0,0,0};
#pragma unroll
  for (int k = 0; k < 4; k++){
    int d = t + 256*k;
    double x = (double)xq[d];
#pragma unroll
    for (int c = 0; c < 5; c++) acc[c] += x*(double)protoNr[c*DD + d];
  }
  __shared__ double red[4][5];
  __shared__ int isLast;
#pragma unroll
  for (int c = 0; c < 5; c++) acc[c] = wave_reduce_d(acc[c]);
  if ((t & 63) == 0){
#pragma unroll
    for (int c = 0; c < 5; c++) red[t >> 6][c] = acc[c];
  }
  __syncthreads();
  if (t == 0){
    double x2 = p2d[NK+q];
    double v[5]; double mx = -1e300;
#pragma unroll
    for (int c = 0; c < 5; c++){
      double mk2N = mk2Np[c*4+0]+mk2Np[c*4+1]+mk2Np[c*4+2]+mk2Np[c*4+3];
      double sfN  = 1.0/(1.0 + sqrt(fmax(1.0 - CCd*mk2N, 0.0)));
      double dot  = sfN*(red[0][c] + red[1][c] + red[2][c] + red[3][c]);
      v[c] = -hyp_dist_d(dot, x2, mk2N*sfN*sfN);
      mx = fmax(mx, v[c]);
    }
    double se = 0.0;
#pragma unroll
    for (int c = 0; c < 5; c++){ v[c] = exp(v[c]-mx); se += v[c]; }
    double inv = 1.0/se;
#pragma unroll
    for (int c = 0; c < 5; c++) out[q*5 + c] = (float)(v[c]*inv);

    // ll = log_softmax(log_softmax(-distS)); lossQ = ll[label]
    double u[5]; mx = -1e300;
#pragma unroll
    for (int c = 0; c < 5; c++){ u[c] = -distS[q*5+c]; mx = fmax(mx, u[c]); }
    double s1 = 0.0;
#pragma unroll
    for (int c = 0; c < 5; c++) s1 += exp(u[c]-mx);
    double lse1 = mx + log(s1);
#pragma unroll
    for (int c = 0; c < 5; c++) u[c] -= lse1;
    double mx2 = -1e300;
#pragma unroll
    for (int c = 0; c < 5; c++) mx2 = fmax(mx2, u[c]);
    double s2 = 0.0;
#pragma unroll
    for (int c = 0; c < 5; c++) s2 += exp(u[c]-mx2);
    double lse2 = mx2 + log(s2);
    lossQ[q] = u[label[NQ + q]] - lse2;

    // release: make lossQ[q] visible device-wide, then count completion
    __threadfence();
    isLast = (atomicAdd(cnt, 1) == NQ - 1) ? 1 : 0;
  }
  __syncthreads();
  if (isLast){
    __threadfence();                        // acquire: invalidate stale L2 lines
    double v = (t < NQ) ? lossQ[t] : 0.0;
    v = wave_reduce_d(v);
    __shared__ double redL[4];
    if ((t & 63) == 0) redL[t >> 6] = v;
    __syncthreads();
    if (t == 0) out[NQ*KCLS] = (float)(-(redL[0]+redL[1]+redL[2]+redL[3])/75.0);
  }
}

extern "C" void kernel_launch(void* const* d_in, const int* in_sizes, int n_in,
                              void* d_out, int out_size, void* d_ws, size_t ws_size,
                              hipStream_t stream) {
  const float* feat  = (const float*)d_in[0];
  const int*   label = (const int*)d_in[1];
  const float* noise = (const float*)d_in[2];
  float* out = (float*)d_out;

  // ws layout (doubles start at 105*1024*4 = 430080 B, 8-aligned)
  float*  P        = (float*)d_ws;
  float*  protoNr  = P + NROWS*DD;           // unscaled new prototypes
  double* p2d      = (double*)(protoNr + KCLS*DD);
  double* distS    = p2d + NROWS;
  double* lossQ    = distS + NQ*KCLS;
  double* std_g    = lossQ + NQ;
  double* mkr_g    = std_g + KCLS*DD;
  double* mk2part  = mkr_g + KCLS*DD;        // [20] (pad 32)
  double* coefS_g  = mk2part + 32;
  double* coefV_g  = coefS_g + KCLS*NAUG;
  double* lamJ_g   = coefV_g + KCLS*NAUG;
  double* mk2Np    = lamJ_g + KCLS*NAUG;     // [20] (pad 32)
  int*    predS    = (int*)(mk2Np + 32);
  int*    cnt      = predS + NQ;

  k_expmap<<<NROWS, 256, 0, stream>>>(feat, P, p2d, cnt);
  k_dist1 <<<NQ, 256, 0, stream>>>(P, p2d, distS, predS);
  k_stats <<<4*KCLS, 256, 0, stream>>>(feat, P, p2d, predS, std_g, mkr_g, mk2part);
  k_coef  <<<dim3(NAUG, KCLS), 256, 0, stream>>>(noise, std_g, mkr_g, mk2part,
                                                 coefS_g, coefV_g, lamJ_g);
  k_asm   <<<4*KCLS, 256, 0, stream>>>(noise, P, p2d, std_g, mkr_g, mk2part,
                                       coefS_g, coefV_g, lamJ_g, protoNr, mk2Np);
  k_dist2 <<<NQ, 256, 0, stream>>>(P, protoNr, p2d, mk2Np, distS, label, out,
                                   lossQ, cnt);
}